// Round 13
// baseline (189.572 us; speedup 1.0000x reference)
//
#include <hip/hip_runtime.h>
#include <hip/hip_bf16.h>
#include <math.h>

#define BATCH 4
#define SEQ   4096
#define EMB   1024
#define HD    64

#define QBLK  64    // query rows per attention block (4 waves x 16)
#define KBLK  64    // key/value tile
#define CHUNK 512   // split-K chunk (8 tiles)
#define BM    16    // GEMM rows per block (grid 1024)

// per-batch split-K block count: sum_{c=0..7} (64-8c) = 288
#define NSPB  288
#define NSLOT (BATCH * NSPB)

// scores scaled into log2 domain: 1/sqrt(64) * log2(e)  (folded into Q)
#define SCL   0.1803368801111204f

typedef _Float16 half8 __attribute__((ext_vector_type(8)));
typedef _Float16 half4 __attribute__((ext_vector_type(4)));
typedef float    f32x4 __attribute__((ext_vector_type(4)));

// global->LDS direct staging, 16B per lane, linear LDS dest (wave base + lane*16)
#define GLOAD_LDS16(g, l) __builtin_amdgcn_global_load_lds(                 \
    (const __attribute__((address_space(1))) void*)(g),                     \
    (__attribute__((address_space(3))) void*)(l), 16, 0, 0)

// DPP lane-move within 16-lane row (full-rate VALU, no DS pipe).
#define DPPF(v, ctrl) __int_as_float(__builtin_amdgcn_update_dpp(           \
    0, __float_as_int(v), ctrl, 0xF, 0xF, true))

static __device__ __forceinline__ float bf2f(unsigned int u16) {
    union { unsigned int i; float f; } v;
    v.i = u16 << 16;
    return v.f;
}

// --------- dtype detector: bf16 N(0,1) never has exponent>146; fp32 read as
// --------- bf16 halfwords does (~42% of low halves). Deterministic per input.
__global__ void detect_dtype(const unsigned short* __restrict__ x,
                             int* __restrict__ flag)
{
    const int tid = threadIdx.x;
    int big = 0;
    for (int i = tid; i < 2048; i += 64) {
        const int e = (x[i] >> 7) & 0xff;
        if (e > 146) big++;                 // |bf16| > ~1e6 (incl inf/nan)
    }
    #pragma unroll
    for (int off = 32; off; off >>= 1) big += __shfl_xor(big, off);
    if (tid == 0) *flag = (big > 200) ? 0 : 1;   // 0 = fp32 inputs, 1 = bf16
}

// ---------------- W -> fp16, FRAGMENT-ORDERED [tk=k/32][n=192][32] --------
// dst = (tk*192 + n)*32 + (k % 32): a wave's B-frag read is 1 KB contiguous.
__global__ __launch_bounds__(256) void w_to_fp16t(
    const void* __restrict__ Wqp, const void* __restrict__ Wkp,
    const void* __restrict__ Wvp, const int* __restrict__ flagp,
    _Float16* __restrict__ Wt)
{
    const int gid = blockIdx.x * 256 + threadIdx.x;   // 24576 threads
    const int n   = gid >> 7;                         // 0..191
    const int kc  = (gid & 127) << 3;                 // k chunk base (step 8)
    const int mat = n >> 6, d = n & 63;
    const void* Wp = (mat == 0) ? Wqp : (mat == 1 ? Wkp : Wvp);

    half8 o;
    if (*flagp) {
        const unsigned short* W = (const unsigned short*)Wp;
        #pragma unroll
        for (int j = 0; j < 8; ++j) o[j] = (_Float16)bf2f(W[(kc + j) * HD + d]);
    } else {
        const float* W = (const float*)Wp;
        #pragma unroll
        for (int j = 0; j < 8; ++j) o[j] = (_Float16)W[(kc + j) * HD + d];
    }
    const int tk = kc >> 5;                           // 32-wide k tile
    *(half8*)&Wt[((tk * 192) + n) * 32 + (kc & 31)] = o;
}

// ---------------- QKV projection: barrier-free register GEMM --------------
// [16384 x 1024] x [1024 x 192]. BM=16 rows/block, 1024 blocks, 4 waves x
// 48 cols. NO LDS, NO __syncthreads: A-fragments load DIRECTLY from global
// x into registers (wave reads 16 rows x 64B fully-used lines; 4 waves'
// redundant reads are L1-served). Rationale: every prior variant was pinned
// at ~40us because the per-tile barrier forces vmcnt(0) drain of the x
// prefetch (compiler emits full waitcnt before s_barrier) -- with no
// barriers, loads pipeline freely and stalls are per-wave, hidden by TLP.
template<bool ISBF>
static __device__ __forceinline__ void qkv_body(
    const void* __restrict__ xp, const _Float16* __restrict__ Wt,
    _Float16* __restrict__ Qh, _Float16* __restrict__ Kh,
    _Float16* __restrict__ Vth)
{
    const int tid  = threadIdx.x;
    const int w    = tid >> 6;
    const int lane = tid & 63;
    const int c15  = lane & 15;
    const int kg   = lane >> 4;
    const size_t row0 = (size_t)blockIdx.x * BM;

    // A-frag source: row (row0+c15), halves t*64 + kk*32 + kg*8 .. +8
    const size_t abase  = (row0 + c15) * EMB + kg * 8;
    const int    wtbase = (w * 48 + c15) * 32 + kg * 8;

    struct ARaw { uint4 u0, u1; float4 g0[2], g1[2]; };

    auto lda = [&](int t, ARaw& r) {
        if constexpr (ISBF) {
            const unsigned short* xb =
                (const unsigned short*)xp + abase + (size_t)t * 64;
            r.u0 = *(const uint4*)xb;
            r.u1 = *(const uint4*)(xb + 32);
        } else {
            const float* xf = (const float*)xp + abase + (size_t)t * 64;
            r.g0[0] = *(const float4*)(xf);
            r.g0[1] = *(const float4*)(xf + 4);
            r.g1[0] = *(const float4*)(xf + 32);
            r.g1[1] = *(const float4*)(xf + 36);
        }
    };
    auto cvt = [&](const uint4& u, const float4* g) -> half8 {
        half8 h;
        if constexpr (ISBF) {
            const unsigned int uu[4] = {u.x, u.y, u.z, u.w};
            #pragma unroll
            for (int q = 0; q < 4; ++q) {
                h[2 * q]     = (_Float16)bf2f(uu[q] & 0xffffu);
                h[2 * q + 1] = (_Float16)bf2f(uu[q] >> 16);
            }
        } else {
            const float ff[8] = {g[0].x, g[0].y, g[0].z, g[0].w,
                                 g[1].x, g[1].y, g[1].z, g[1].w};
            #pragma unroll
            for (int q = 0; q < 8; ++q) h[q] = (_Float16)ff[q];
        }
        return h;
    };
    auto ldb = [&](int t, half8* bf) {
        #pragma unroll
        for (int kk = 0; kk < 2; ++kk)
            #pragma unroll
            for (int nf = 0; nf < 3; ++nf)
                bf[kk * 3 + nf] = *(const half8*)&Wt[
                    (t * 2 + kk) * 192 * 32 + nf * 16 * 32 + wtbase];
    };

    f32x4 acc[3];
    #pragma unroll
    for (int nf = 0; nf < 3; ++nf) acc[nf] = (f32x4){0.f, 0.f, 0.f, 0.f};

    auto compute = [&](const ARaw& r, const half8* bf) {
        const half8 a0 = cvt(r.u0, r.g0);
        const half8 a1 = cvt(r.u1, r.g1);
        #pragma unroll
        for (int nf = 0; nf < 3; ++nf)
            acc[nf] = __builtin_amdgcn_mfma_f32_16x16x32_f16(
                a0, bf[nf], acc[nf], 0, 0, 0);
        #pragma unroll
        for (int nf = 0; nf < 3; ++nf)
            acc[nf] = __builtin_amdgcn_mfma_f32_16x16x32_f16(
                a1, bf[3 + nf], acc[nf], 0, 0, 0);
    };

    // 2-deep register pipeline, static set selection (rule 20), no barriers.
    ARaw  r0, r1;
    half8 b0[6], b1[6];
    lda(0, r0); ldb(0, b0);
    lda(1, r1); ldb(1, b1);

    for (int tt = 0; tt < 16; tt += 2) {
        compute(r0, b0);
        if (tt + 2 < 16) { lda(tt + 2, r0); ldb(tt + 2, b0); }
        compute(r1, b1);
        if (tt + 3 < 16) { lda(tt + 3, r1); ldb(tt + 3, b1); }
    }

    // epilogue: C layout row = kg*4+r, col = c15 (verified round 12)
    #pragma unroll
    for (int nf = 0; nf < 3; ++nf) {
        const int nc  = w * 48 + nf * 16;
        const int mat = nc >> 6;
        const int d   = (nc & 63) + c15;
        if (mat < 2) {
            _Float16* Out = mat ? Kh : Qh;
            const float qs = mat ? 1.f : SCL;     // pre-scale Q by SCL
            #pragma unroll
            for (int r = 0; r < 4; ++r)
                Out[(row0 + kg * 4 + r) * HD + d] = (_Float16)(acc[nf][r] * qs);
        } else {
            const int bb = (int)(row0 >> 12);
            const int s0 = (int)(row0 & 4095);
            half4 hv;
            #pragma unroll
            for (int r = 0; r < 4; ++r) hv[r] = (_Float16)acc[nf][r];
            *(half4*)&Vth[((size_t)bb * HD + d) * SEQ + s0 + kg * 4] = hv;
        }
    }
}

__global__ __launch_bounds__(256) void qkv_gemm(
    const void* __restrict__ xp, const _Float16* __restrict__ Wt,
    const int* __restrict__ flagp,
    _Float16* __restrict__ Qh, _Float16* __restrict__ Kh,
    _Float16* __restrict__ Vth)
{
    if (*flagp) qkv_body<true >(xp, Wt, Qh, Kh, Vth);
    else        qkv_body<false>(xp, Wt, Qh, Kh, Vth);
}

// ---------------- split-K causal flash attention --------------------------
// Block = (batch, qtile of 64 rows, 512-key chunk). 4 waves x 16 rows.
// Row-sum l via MFMA-with-ones fused into the PV cluster; scores arrive
// pre-scaled (SCL folded into Q); DPP max-reduce; defer-max (THR=4 log2).
__global__ __launch_bounds__(256) void attn_split(
    const _Float16* __restrict__ Qh, const _Float16* __restrict__ Kh,
    const _Float16* __restrict__ Vth,
    _Float16* __restrict__ PoG, float* __restrict__ PmG,
    float* __restrict__ PlG)
{
    __shared__ _Float16 Kt[2][KBLK * HD];    // 2 x 8 KB  [key][dim]
    __shared__ _Float16 Vt[2][HD * KBLK];    // 2 x 8 KB  [dim][key]
    __shared__ _Float16 Ps[4][16 * KBLK];    // 2 KB per wave, P re-shape

    const int b = blockIdx.y;
    const int f = blockIdx.x;                // 0..287: (chunk c, qtile qb)
    int c = 0, off = 0, cnt = 64;
    while (f >= off + cnt) { off += cnt; ++c; cnt -= 8; }
    const int qb = 8 * c + (f - off);
    const int q0 = qb * QBLK;
    const int kstart = c * CHUNK;
    const int kend   = min(kstart + CHUNK, q0 + QBLK);
    const int nt     = (kend - kstart) / KBLK;

    const int tid  = threadIdx.x;
    const int w    = tid >> 6;       // wave: rows q0+16w .. q0+16w+15
    const int lane = tid & 63;
    const int col  = lane & 15;      // MFMA col / A row selector
    const int kg   = lane >> 4;      // k-chunk selector (0..3)

    const size_t bo = (size_t)b * SEQ;
    const _Float16* Kb = Kh + bo * HD;
    const _Float16* Vb = Vth + (size_t)b * HD * SEQ;

    // Q A-fragments (row = lane&15, k = kg*8 + j), kept in registers
    const _Float16* Qp = Qh + (bo + q0 + w * 16 + col) * HD;
    const half8 aq0 = *(const half8*)(Qp + kg * 8);
    const half8 aq1 = *(const half8*)(Qp + 32 + kg * 8);

    // ones B-fragment for the l-sum MFMA
    half8 vone;
    #pragma unroll
    for (int j = 0; j < 8; ++j) vone[j] = (_Float16)1.0f;

    f32x4 O[4];
    f32x4 Ls = (f32x4){0.f, 0.f, 0.f, 0.f};   // row-sums, row = kg*4+r
    float mreg[4];
    #pragma unroll
    for (int cq = 0; cq < 4; ++cq) O[cq] = (f32x4){0.f, 0.f, 0.f, 0.f};
    #pragma unroll
    for (int r = 0; r < 4; ++r) mreg[r] = -INFINITY;

    // stage one 64x64 fp16 tile: waves 0-1 K, waves 2-3 V^T (4 GLOADs each).
    const int wh = w & 1;
    auto stage = [&](int t, int buf) {
        const int k0 = kstart + t * KBLK;
        if (w < 2) {
            const _Float16* g = Kb + (size_t)k0 * HD;
            #pragma unroll
            for (int i = 0; i < 4; ++i) {
                const int c2 = (wh * 4 + i) * 64 + lane;   // 16B chunk id
                const int key = c2 >> 3, slot = c2 & 7;
                GLOAD_LDS16(g + key * HD + ((slot ^ (key & 7)) << 3),
                            &Kt[buf][(wh * 4 + i) * 512]);
            }
        } else {
            const _Float16* g = Vb + k0;
            #pragma unroll
            for (int i = 0; i < 4; ++i) {
                const int c2 = (wh * 4 + i) * 64 + lane;
                const int dim = c2 >> 3, slot = c2 & 7;
                GLOAD_LDS16(g + (size_t)dim * SEQ + ((slot ^ (dim & 7)) << 3),
                            &Vt[buf][(wh * 4 + i) * 512]);
            }
        }
    };

    stage(0, 0);
    int cur = 0;

    for (int t = 0; t < nt; ++t) {
        __syncthreads();                       // tile t staged; tile t-1 reads done
        if (t + 1 < nt) stage(t + 1, cur ^ 1); // prefetch overlaps compute

        const int k0 = kstart + t * KBLK;

        // ---- S = Q K^T  (4 col-tiles x 2 k-steps); scores already scaled
        f32x4 S[4];
        __builtin_amdgcn_s_setprio(1);
        #pragma unroll
        for (int cq = 0; cq < 4; ++cq) {
            const int key = cq * 16 + col;
            const int sw  = key & 7;
            const half8 bk0 = *(const half8*)&Kt[cur][(key * 8 + (kg ^ sw)) * 8];
            const half8 bk1 = *(const half8*)&Kt[cur][(key * 8 + ((4 + kg) ^ sw)) * 8];
            f32x4 acc = (f32x4){0.f, 0.f, 0.f, 0.f};
            acc = __builtin_amdgcn_mfma_f32_16x16x32_f16(aq0, bk0, acc, 0, 0, 0);
            acc = __builtin_amdgcn_mfma_f32_16x16x32_f16(aq1, bk1, acc, 0, 0, 0);
            S[cq] = acc;
        }
        __builtin_amdgcn_s_setprio(0);

        // ---- causal mask (log2-domain scores already)
        const int rowb  = q0 + w * 16 + kg * 4;
        const bool full = (k0 + KBLK - 1) <= (q0 + w * 16);
        float p[4][4];
        #pragma unroll
        for (int cq = 0; cq < 4; ++cq) {
            const int key = k0 + cq * 16 + col;
            #pragma unroll
            for (int r = 0; r < 4; ++r) {
                float s = S[cq][r];
                if (!full && key > rowb + r) s = -INFINITY;
                p[cq][r] = s;
            }
        }

        // ---- row max via DPP butterfly (full-rate VALU, no DS traffic)
        float vmax[4];
        #pragma unroll
        for (int r = 0; r < 4; ++r) {
            float v = fmaxf(fmaxf(p[0][r], p[1][r]), fmaxf(p[2][r], p[3][r]));
            v = fmaxf(v, DPPF(v, 0xB1));
            v = fmaxf(v, DPPF(v, 0x4E));
            v = fmaxf(v, DPPF(v, 0x141));
            v = fmaxf(v, DPPF(v, 0x140));
            vmax[r] = v;
        }

        // ---- defer-max (T13): only rescale when max grew > 4 (log2 units).
        bool grow = false;
        #pragma unroll
        for (int r = 0; r < 4; ++r) grow |= (vmax[r] > mreg[r] + 4.0f);
        if (__any(grow)) {                       // wave-uniform branch
            #pragma unroll
            for (int r = 0; r < 4; ++r) {
                const float mn = fmaxf(mreg[r], vmax[r]);   // finite from tile 0
                const float al = exp2f(mreg[r] - mn);  // first tile: exp2(-inf)=0
                mreg[r] = mn;
                Ls[r] *= al;
                #pragma unroll
                for (int cq = 0; cq < 4; ++cq)
                    O[cq][r] *= al;
            }
        }

        // ---- P = exp2(s-m); write to swizzled LDS for the PV A-fragment
        #pragma unroll
        for (int cq = 0; cq < 4; ++cq) {
            const int colidx = cq * 16 + col;
            #pragma unroll
            for (int r = 0; r < 4; ++r) {
                const float pv = exp2f(p[cq][r] - mreg[r]);  // masked -> 0
                const int row = kg * 4 + r;
                Ps[w][row * 64 + (colidx ^ ((row & 7) << 3))] = (_Float16)pv;
            }
        }

        // ---- O += P V, Ls += P*1  (same-wave LDS RAW: in-order DS pipe)
        __builtin_amdgcn_s_setprio(1);
        #pragma unroll
        for (int s2 = 0; s2 < 2; ++s2) {
            const int prow = col;                         // A row = lane&15
            const half8 pa = *(const half8*)&Ps[w][prow * 64 +
                ((s2 * 32 + kg * 8) ^ ((prow & 7) << 3))];
            #pragma unroll
            for (int cq = 0; cq < 4; ++cq) {
                const int dim = cq * 16 + col;
                const half8 bv = *(const half8*)&Vt[cur][(dim * 8 +
                    ((s2 * 4 + kg) ^ (dim & 7))) * 8];
                O[cq] = __builtin_amdgcn_mfma_f32_16x16x32_f16(pa, bv, O[cq], 0, 0, 0);
            }
            Ls = __builtin_amdgcn_mfma_f32_16x16x32_f16(pa, vone, Ls, 0, 0, 0);
        }
        __builtin_amdgcn_s_setprio(0);
        cur ^= 1;
    }

    // ---- write partial (unnormalized O fp16, m/l fp32)
    const int pslot = b * NSPB + f;
    #pragma unroll
    for (int cq = 0; cq < 4; ++cq)
        #pragma unroll
        for (int r = 0; r < 4; ++r) {
            const int rloc = w * 16 + kg * 4 + r;
            PoG[((size_t)pslot * 64 + rloc) * 64 + cq * 16 + col] =
                (_Float16)O[cq][r];
        }
    if (col == 0) {
        #pragma unroll
        for (int r = 0; r < 4; ++r) {
            const int rloc = w * 16 + kg * 4 + r;
            PmG[pslot * 64 + rloc] = mreg[r];
            PlG[pslot * 64 + rloc] = Ls[r];
        }
    }
}

// ---------------- merge <=8 chunk partials per qtile ----------------------
// 1024 blocks x 128 threads; thread owns 8 contiguous dims of one row
// (half8 16B loads of Po).
__global__ __launch_bounds__(128) void attn_merge(
    const _Float16* __restrict__ PoG, const float* __restrict__ PmG,
    const float* __restrict__ PlG, const int* __restrict__ flagp,
    void* __restrict__ outp)
{
    const int qb   = blockIdx.x;             // 0..63
    const int b    = blockIdx.y;             // 0..3
    const int rg   = blockIdx.z;             // 0..3: rows rg*16..rg*16+15
    const int nc   = (qb >> 3) + 1;          // chunk count for this qtile
    const int tid  = threadIdx.x;
    const int rloc = rg * 16 + (tid >> 3);   // row within qtile
    const int d0   = (tid & 7) * 8;          // dim base, 8 per thread
    const int isbf = *flagp;

    // pass 1: global max (slot(i) = b*NSPB + i*(68-4i) + qb - 8i)
    float mm = -INFINITY;
    for (int i = 0; i < nc; ++i) {
        const int sl = b * NSPB + i * (68 - 4 * i) + qb - 8 * i;
        mm = fmaxf(mm, PmG[sl * 64 + rloc]);
    }
    // pass 2: weighted combine (Pm/Pl re-read: L2-hot, broadcast in 8-lane grp)
    float acc[8] = {0.f, 0.f, 0.f, 0.f, 0.f, 0.f, 0.f, 0.f};
    float ls = 0.f;
    for (int i = 0; i < nc; ++i) {
        const int sl = b * NSPB + i * (68 - 4 * i) + qb - 8 * i;
        const float wsc = exp2f(PmG[sl * 64 + rloc] - mm);
        const half8 po = *(const half8*)&PoG[((size_t)sl * 64 + rloc) * 64 + d0];
        #pragma unroll
        for (int j = 0; j < 8; ++j) acc[j] += wsc * (float)po[j];
        ls += wsc * PlG[sl * 64 + rloc];
    }
    const float il = 1.f / ls;
    const size_t obase = ((size_t)b * SEQ + qb * QBLK + rloc) * HD + d0;
    if (isbf) {
        __hip_bfloat16* Ob = (__hip_bfloat16*)outp;
        #pragma unroll
        for (int j = 0; j < 8; ++j) Ob[obase + j] = __float2bfloat16(acc[j] * il);
    } else {
        float* Of = (float*)outp;
        #pragma unroll
        for (int j = 0; j < 8; ++j) Of[obase + j] = acc[j] * il;
    }
}

extern "C" void kernel_launch(void* const* d_in, const int* in_sizes, int n_in,
                              void* d_out, int out_size, void* d_ws, size_t ws_size,
                              hipStream_t stream)
{
    const void* x  = d_in[0];
    const void* Wq = d_in[1];
    const void* Wk = d_in[2];
    const void* Wv = d_in[3];

    const size_t N = (size_t)BATCH * SEQ * HD;          // 1,048,576
    int*      flag = (int*)d_ws;
    _Float16* Qh   = (_Float16*)((char*)d_ws + 256);    // 3 x 2 MB fp16
    _Float16* Kh   = Qh + N;
    _Float16* Vth  = Kh + N;
    _Float16* Wt   = Vth + N;                           // 384 KB fp16 frag-ordered
    float*    PmG  = (float*)(Wt + 192 * 1024);         // 288 KB
    float*    PlG  = PmG + (size_t)NSLOT * 64;          // 288 KB
    _Float16* PoG  = (_Float16*)(PlG + (size_t)NSLOT * 64);  // 9.4 MB fp16

    detect_dtype<<<1, 64, 0, stream>>>((const unsigned short*)x, flag);

    w_to_fp16t<<<96, 256, 0, stream>>>(Wq, Wk, Wv, flag, Wt);

    qkv_gemm<<<BATCH * SEQ / BM, 256, 0, stream>>>(x, Wt, flag, Qh, Kh, Vth);

    attn_split<<<dim3(NSPB, BATCH), 256, 0, stream>>>(Qh, Kh, Vth,
                                                      PoG, PmG, PlG);

    attn_merge<<<dim3(SEQ / QBLK, BATCH, 4), 128, 0, stream>>>(PoG, PmG, PlG,
                                                               flag, d_out);
}

// Round 14
// 157.381 us; speedup vs baseline: 1.2045x; 1.2045x over previous
//
#include <hip/hip_runtime.h>
#include <hip/hip_bf16.h>
#include <math.h>

#define BATCH 4
#define SEQ   4096
#define EMB   1024
#define HD    64

#define QBLK  64    // query rows per attention block (4 waves x 16)
#define KBLK  64    // key/value tile
#define CHUNK 512   // split-K chunk (8 tiles)
#define BM    32    // GEMM rows per block (best-measured config, round 10)

// per-batch split-K block count: sum_{c=0..7} (64-8c) = 288
#define NSPB  288
#define NSLOT (BATCH * NSPB)

// scores scaled into log2 domain: 1/sqrt(64) * log2(e)  (folded into Q)
#define SCL   0.1803368801111204f

typedef _Float16 half8 __attribute__((ext_vector_type(8)));
typedef _Float16 half4 __attribute__((ext_vector_type(4)));
typedef float    f32x4 __attribute__((ext_vector_type(4)));

// global->LDS direct staging, 16B per lane, linear LDS dest (wave base + lane*16)
#define GLOAD_LDS16(g, l) __builtin_amdgcn_global_load_lds(                 \
    (const __attribute__((address_space(1))) void*)(g),                     \
    (__attribute__((address_space(3))) void*)(l), 16, 0, 0)

// DPP lane-move within 16-lane row (full-rate VALU, no DS pipe).
#define DPPF(v, ctrl) __int_as_float(__builtin_amdgcn_update_dpp(           \
    0, __float_as_int(v), ctrl, 0xF, 0xF, true))

static __device__ __forceinline__ float bf2f(unsigned int u16) {
    union { unsigned int i; float f; } v;
    v.i = u16 << 16;
    return v.f;
}

// ---------------- W -> fp16, FRAGMENT-ORDERED [tk=k/32][n=192][32] --------
// dst = (tk*192 + n)*32 + (k % 32): a wave's B-frag read is 1 KB contiguous.
// dtype detection FUSED here (saves one serialized launch): wave 0 of every
// block reads x[0..2048) (L2-hot, ~2KB) -- bf16 N(0,1) never has exponent
// >146; fp32 read as bf16 halfwords does (~42% of low halves). Block-local
// result in LDS; every block also writes the global flag (same value,
// benign) for the downstream kernels.
__global__ __launch_bounds__(256) void w_to_fp16t(
    const unsigned short* __restrict__ x,
    const void* __restrict__ Wqp, const void* __restrict__ Wkp,
    const void* __restrict__ Wvp, int* __restrict__ flag,
    _Float16* __restrict__ Wt)
{
    __shared__ int sflag;
    const int tid = threadIdx.x;
    if (tid < 64) {
        int big = 0;
        for (int i = tid; i < 2048; i += 64) {
            const int e = (x[i] >> 7) & 0xff;
            if (e > 146) big++;             // |bf16| > ~1e6 (incl inf/nan)
        }
        #pragma unroll
        for (int off = 32; off; off >>= 1) big += __shfl_xor(big, off);
        if (tid == 0) {
            sflag = (big > 200) ? 0 : 1;    // 0 = fp32 inputs, 1 = bf16
            *flag = sflag;
        }
    }
    __syncthreads();
    const int isbf = sflag;

    const int gid = blockIdx.x * 256 + tid;           // 24576 threads
    const int n   = gid >> 7;                         // 0..191
    const int kc  = (gid & 127) << 3;                 // k chunk base (step 8)
    const int mat = n >> 6, d = n & 63;
    const void* Wp = (mat == 0) ? Wqp : (mat == 1 ? Wkp : Wvp);

    half8 o;
    if (isbf) {
        const unsigned short* W = (const unsigned short*)Wp;
        #pragma unroll
        for (int j = 0; j < 8; ++j) o[j] = (_Float16)bf2f(W[(kc + j) * HD + d]);
    } else {
        const float* W = (const float*)Wp;
        #pragma unroll
        for (int j = 0; j < 8; ++j) o[j] = (_Float16)W[(kc + j) * HD + d];
    }
    const int tk = kc >> 5;                           // 32-wide k tile
    *(half8*)&Wt[((tk * 192) + n) * 32 + (kc & 31)] = o;
}

// ---------------- QKV projection as fp16 MFMA GEMM ------------------------
// [16384 x 1024] x [1024 x 192]. BM=32 rows/block, 512 blocks, 4 waves.
// x reg-staged 2-deep; B-frags coalesced (frag-ordered Wt) + reg-dbuf.
// Q output is pre-scaled by SCL (removes 16 v_mul/tile from attn_split).
// [Reverted to the best-measured round-10 configuration: BM=16 occupancy 2x
//  was time-neutral; barrier-free regressed 1.5x (uncoalesced A-gathers).]
__global__ __launch_bounds__(256) void qkv_gemm(
    const void* __restrict__ xp, const _Float16* __restrict__ Wt,
    const int* __restrict__ flagp,
    _Float16* __restrict__ Qh, _Float16* __restrict__ Kh,
    _Float16* __restrict__ Vth)
{
    __shared__ _Float16 Xs[2][BM * 64];   // 2 x 4 KB, 16B-slot swizzle ^= row&7

    const int tid  = threadIdx.x;
    const int w    = tid >> 6;
    const int lane = tid & 63;
    const int c15  = lane & 15;
    const int kg   = lane >> 4;
    const size_t row0 = (size_t)blockIdx.x * BM;
    const int isbf = *flagp;

    const int sr = tid >> 3, ss = tid & 7;
    const size_t gbase = (row0 + sr) * EMB + ss * 8;
    const int lidx = sr * 64 + ((ss ^ (sr & 7)) << 3);

    // per-thread base into fragment-ordered Wt: (tk*192 + n)*32 + kg*8
    const int wtbase = (w * 48 + c15) * 32 + kg * 8;

    float4 f0[2], f1[2];     // two in-flight x staging sets
    uint4  u0,    u1;

    auto ldc = [&](int t, float4* f, uint4* u) {
        if (isbf) *u = *(const uint4*)((const unsigned short*)xp + gbase + t * 64);
        else {
            f[0] = *(const float4*)((const float*)xp + gbase + t * 64);
            f[1] = *(const float4*)((const float*)xp + gbase + t * 64 + 4);
        }
    };
    auto wrc = [&](int buf, const float4* f, const uint4* u) {
        half8 h;
        if (isbf) {
            const unsigned int uu[4] = {u->x, u->y, u->z, u->w};
            #pragma unroll
            for (int q = 0; q < 4; ++q) {
                h[2 * q]     = (_Float16)bf2f(uu[q] & 0xffffu);
                h[2 * q + 1] = (_Float16)bf2f(uu[q] >> 16);
            }
        } else {
            const float ff[8] = {f[0].x, f[0].y, f[0].z, f[0].w,
                                 f[1].x, f[1].y, f[1].z, f[1].w};
            #pragma unroll
            for (int q = 0; q < 8; ++q) h[q] = (_Float16)ff[q];
        }
        *(half8*)&Xs[buf][lidx] = h;
    };

    half8 bf0[6], bf1[6];
    auto ldb = [&](int t, half8* bf) {
        #pragma unroll
        for (int kk = 0; kk < 2; ++kk)
            #pragma unroll
            for (int nf = 0; nf < 3; ++nf)
                bf[kk * 3 + nf] = *(const half8*)&Wt[
                    (t * 2 + kk) * 192 * 32 + nf * 16 * 32 + wtbase];
    };

    f32x4 acc[2][3];
    #pragma unroll
    for (int mf = 0; mf < 2; ++mf)
        #pragma unroll
        for (int nf = 0; nf < 3; ++nf) acc[mf][nf] = (f32x4){0.f, 0.f, 0.f, 0.f};

    auto compute = [&](int buf, const half8* bf) {
        #pragma unroll
        for (int kk = 0; kk < 2; ++kk) {
            half8 a[2];
            #pragma unroll
            for (int mf = 0; mf < 2; ++mf) {
                const int R = mf * 16 + c15;
                a[mf] = *(const half8*)&Xs[buf][R * 64 +
                        (((kk * 4 + kg) ^ (R & 7)) << 3)];
            }
            #pragma unroll
            for (int mf = 0; mf < 2; ++mf)
                #pragma unroll
                for (int nf = 0; nf < 3; ++nf)
                    acc[mf][nf] = __builtin_amdgcn_mfma_f32_16x16x32_f16(
                        a[mf], bf[kk * 3 + nf], acc[mf][nf], 0, 0, 0);
        }
    };

    // prologue: tile0 staged + B0 in regs; tile1 x-load in flight
    ldc(0, f0, &u0);
    ldb(0, bf0);
    wrc(0, f0, &u0);
    ldc(1, f1, &u1);

    for (int tt = 0; tt < 16; tt += 2) {
        __syncthreads();                          // Xs[0] (tile tt) ready
        if (tt + 2 < 16) ldc(tt + 2, f0, &u0);
        ldb(tt + 1, bf1);
        compute(0, bf0);
        wrc(1, f1, &u1);
        __syncthreads();                          // Xs[1] (tile tt+1) ready
        if (tt + 3 < 16) ldc(tt + 3, f1, &u1);
        if (tt + 2 < 16) ldb(tt + 2, bf0);
        compute(1, bf1);
        if (tt + 2 < 16) wrc(0, f0, &u0);
    }

    #pragma unroll
    for (int nf = 0; nf < 3; ++nf) {
        const int nc  = w * 48 + nf * 16;
        const int mat = nc >> 6;
        const int d   = (nc & 63) + c15;
        if (mat < 2) {
            _Float16* Out = mat ? Kh : Qh;
            const float qs = mat ? 1.f : SCL;     // pre-scale Q by SCL
            #pragma unroll
            for (int mf = 0; mf < 2; ++mf)
                #pragma unroll
                for (int r = 0; r < 4; ++r)
                    Out[(row0 + mf * 16 + kg * 4 + r) * HD + d] =
                        (_Float16)(acc[mf][nf][r] * qs);
        } else {
            const int bb = (int)(row0 >> 12);
            const int s0 = (int)(row0 & 4095);
            #pragma unroll
            for (int mf = 0; mf < 2; ++mf) {
                half4 hv;
                #pragma unroll
                for (int r = 0; r < 4; ++r) hv[r] = (_Float16)acc[mf][nf][r];
                *(half4*)&Vth[((size_t)bb * HD + d) * SEQ + s0 + mf * 16 + kg * 4] = hv;
            }
        }
    }
}

// ---------------- split-K causal flash attention --------------------------
// Block = (batch, qtile of 64 rows, 512-key chunk). 4 waves x 16 rows.
// Row-sum l via MFMA-with-ones fused into the PV cluster; scores arrive
// pre-scaled (SCL folded into Q); DPP max-reduce; defer-max (THR=4 log2).
__global__ __launch_bounds__(256) void attn_split(
    const _Float16* __restrict__ Qh, const _Float16* __restrict__ Kh,
    const _Float16* __restrict__ Vth,
    _Float16* __restrict__ PoG, float* __restrict__ PmG,
    float* __restrict__ PlG)
{
    __shared__ _Float16 Kt[2][KBLK * HD];    // 2 x 8 KB  [key][dim]
    __shared__ _Float16 Vt[2][HD * KBLK];    // 2 x 8 KB  [dim][key]
    __shared__ _Float16 Ps[4][16 * KBLK];    // 2 KB per wave, P re-shape

    const int b = blockIdx.y;
    const int f = blockIdx.x;                // 0..287: (chunk c, qtile qb)
    int c = 0, off = 0, cnt = 64;
    while (f >= off + cnt) { off += cnt; ++c; cnt -= 8; }
    const int qb = 8 * c + (f - off);
    const int q0 = qb * QBLK;
    const int kstart = c * CHUNK;
    const int kend   = min(kstart + CHUNK, q0 + QBLK);
    const int nt     = (kend - kstart) / KBLK;

    const int tid  = threadIdx.x;
    const int w    = tid >> 6;       // wave: rows q0+16w .. q0+16w+15
    const int lane = tid & 63;
    const int col  = lane & 15;      // MFMA col / A row selector
    const int kg   = lane >> 4;      // k-chunk selector (0..3)

    const size_t bo = (size_t)b * SEQ;
    const _Float16* Kb = Kh + bo * HD;
    const _Float16* Vb = Vth + (size_t)b * HD * SEQ;

    // Q A-fragments (row = lane&15, k = kg*8 + j), kept in registers
    const _Float16* Qp = Qh + (bo + q0 + w * 16 + col) * HD;
    const half8 aq0 = *(const half8*)(Qp + kg * 8);
    const half8 aq1 = *(const half8*)(Qp + 32 + kg * 8);

    // ones B-fragment for the l-sum MFMA
    half8 vone;
    #pragma unroll
    for (int j = 0; j < 8; ++j) vone[j] = (_Float16)1.0f;

    f32x4 O[4];
    f32x4 Ls = (f32x4){0.f, 0.f, 0.f, 0.f};   // row-sums, row = kg*4+r
    float mreg[4];
    #pragma unroll
    for (int cq = 0; cq < 4; ++cq) O[cq] = (f32x4){0.f, 0.f, 0.f, 0.f};
    #pragma unroll
    for (int r = 0; r < 4; ++r) mreg[r] = -INFINITY;

    // stage one 64x64 fp16 tile: waves 0-1 K, waves 2-3 V^T (4 GLOADs each).
    const int wh = w & 1;
    auto stage = [&](int t, int buf) {
        const int k0 = kstart + t * KBLK;
        if (w < 2) {
            const _Float16* g = Kb + (size_t)k0 * HD;
            #pragma unroll
            for (int i = 0; i < 4; ++i) {
                const int c2 = (wh * 4 + i) * 64 + lane;   // 16B chunk id
                const int key = c2 >> 3, slot = c2 & 7;
                GLOAD_LDS16(g + key * HD + ((slot ^ (key & 7)) << 3),
                            &Kt[buf][(wh * 4 + i) * 512]);
            }
        } else {
            const _Float16* g = Vb + k0;
            #pragma unroll
            for (int i = 0; i < 4; ++i) {
                const int c2 = (wh * 4 + i) * 64 + lane;
                const int dim = c2 >> 3, slot = c2 & 7;
                GLOAD_LDS16(g + (size_t)dim * SEQ + ((slot ^ (dim & 7)) << 3),
                            &Vt[buf][(wh * 4 + i) * 512]);
            }
        }
    };

    stage(0, 0);
    int cur = 0;

    for (int t = 0; t < nt; ++t) {
        __syncthreads();                       // tile t staged; tile t-1 reads done
        if (t + 1 < nt) stage(t + 1, cur ^ 1); // prefetch overlaps compute

        const int k0 = kstart + t * KBLK;

        // ---- S = Q K^T  (4 col-tiles x 2 k-steps); scores already scaled
        f32x4 S[4];
        __builtin_amdgcn_s_setprio(1);
        #pragma unroll
        for (int cq = 0; cq < 4; ++cq) {
            const int key = cq * 16 + col;
            const int sw  = key & 7;
            const half8 bk0 = *(const half8*)&Kt[cur][(key * 8 + (kg ^ sw)) * 8];
            const half8 bk1 = *(const half8*)&Kt[cur][(key * 8 + ((4 + kg) ^ sw)) * 8];
            f32x4 acc = (f32x4){0.f, 0.f, 0.f, 0.f};
            acc = __builtin_amdgcn_mfma_f32_16x16x32_f16(aq0, bk0, acc, 0, 0, 0);
            acc = __builtin_amdgcn_mfma_f32_16x16x32_f16(aq1, bk1, acc, 0, 0, 0);
            S[cq] = acc;
        }
        __builtin_amdgcn_s_setprio(0);

        // ---- causal mask (log2-domain scores already)
        const int rowb  = q0 + w * 16 + kg * 4;
        const bool full = (k0 + KBLK - 1) <= (q0 + w * 16);
        float p[4][4];
        #pragma unroll
        for (int cq = 0; cq < 4; ++cq) {
            const int key = k0 + cq * 16 + col;
            #pragma unroll
            for (int r = 0; r < 4; ++r) {
                float s = S[cq][r];
                if (!full && key > rowb + r) s = -INFINITY;
                p[cq][r] = s;
            }
        }

        // ---- row max via DPP butterfly (full-rate VALU, no DS traffic)
        float vmax[4];
        #pragma unroll
        for (int r = 0; r < 4; ++r) {
            float v = fmaxf(fmaxf(p[0][r], p[1][r]), fmaxf(p[2][r], p[3][r]));
            v = fmaxf(v, DPPF(v, 0xB1));
            v = fmaxf(v, DPPF(v, 0x4E));
            v = fmaxf(v, DPPF(v, 0x141));
            v = fmaxf(v, DPPF(v, 0x140));
            vmax[r] = v;
        }

        // ---- defer-max (T13): only rescale when max grew > 4 (log2 units).
        bool grow = false;
        #pragma unroll
        for (int r = 0; r < 4; ++r) grow |= (vmax[r] > mreg[r] + 4.0f);
        if (__any(grow)) {                       // wave-uniform branch
            #pragma unroll
            for (int r = 0; r < 4; ++r) {
                const float mn = fmaxf(mreg[r], vmax[r]);   // finite from tile 0
                const float al = exp2f(mreg[r] - mn);  // first tile: exp2(-inf)=0
                mreg[r] = mn;
                Ls[r] *= al;
                #pragma unroll
                for (int cq = 0; cq < 4; ++cq)
                    O[cq][r] *= al;
            }
        }

        // ---- P = exp2(s-m); write to swizzled LDS for the PV A-fragment
        #pragma unroll
        for (int cq = 0; cq < 4; ++cq) {
            const int colidx = cq * 16 + col;
            #pragma unroll
            for (int r = 0; r < 4; ++r) {
                const float pv = exp2f(p[cq][r] - mreg[r]);  // masked -> 0
                const int row = kg * 4 + r;
                Ps[w][row * 64 + (colidx ^ ((row & 7) << 3))] = (_Float16)pv;
            }
        }

        // ---- O += P V, Ls += P*1  (same-wave LDS RAW: in-order DS pipe)
        __builtin_amdgcn_s_setprio(1);
        #pragma unroll
        for (int s2 = 0; s2 < 2; ++s2) {
            const int prow = col;                         // A row = lane&15
            const half8 pa = *(const half8*)&Ps[w][prow * 64 +
                ((s2 * 32 + kg * 8) ^ ((prow & 7) << 3))];
            #pragma unroll
            for (int cq = 0; cq < 4; ++cq) {
                const int dim = cq * 16 + col;
                const half8 bv = *(const half8*)&Vt[cur][(dim * 8 +
                    ((s2 * 4 + kg) ^ (dim & 7))) * 8];
                O[cq] = __builtin_amdgcn_mfma_f32_16x16x32_f16(pa, bv, O[cq], 0, 0, 0);
            }
            Ls = __builtin_amdgcn_mfma_f32_16x16x32_f16(pa, vone, Ls, 0, 0, 0);
        }
        __builtin_amdgcn_s_setprio(0);
        cur ^= 1;
    }

    // ---- write partial (unnormalized O fp16, m/l fp32)
    const int pslot = b * NSPB + f;
    #pragma unroll
    for (int cq = 0; cq < 4; ++cq)
        #pragma unroll
        for (int r = 0; r < 4; ++r) {
            const int rloc = w * 16 + kg * 4 + r;
            PoG[((size_t)pslot * 64 + rloc) * 64 + cq * 16 + col] =
                (_Float16)O[cq][r];
        }
    if (col == 0) {
        #pragma unroll
        for (int r = 0; r < 4; ++r) {
            const int rloc = w * 16 + kg * 4 + r;
            PmG[pslot * 64 + rloc] = mreg[r];
            PlG[pslot * 64 + rloc] = Ls[r];
        }
    }
}

// ---------------- merge <=8 chunk partials per qtile ----------------------
// 1024 blocks x 128 threads; thread owns 8 contiguous dims of one row
// (half8 16B loads of Po).
__global__ __launch_bounds__(128) void attn_merge(
    const _Float16* __restrict__ PoG, const float* __restrict__ PmG,
    const float* __restrict__ PlG, const int* __restrict__ flagp,
    void* __restrict__ outp)
{
    const int qb   = blockIdx.x;             // 0..63
    const int b    = blockIdx.y;             // 0..3
    const int rg   = blockIdx.z;             // 0..3: rows rg*16..rg*16+15
    const int nc   = (qb >> 3) + 1;          // chunk count for this qtile
    const int tid  = threadIdx.x;
    const int rloc = rg * 16 + (tid >> 3);   // row within qtile
    const int d0   = (tid & 7) * 8;          // dim base, 8 per thread
    const int isbf = *flagp;

    // pass 1: global max (slot(i) = b*NSPB + i*(68-4i) + qb - 8i)
    float mm = -INFINITY;
    for (int i = 0; i < nc; ++i) {
        const int sl = b * NSPB + i * (68 - 4 * i) + qb - 8 * i;
        mm = fmaxf(mm, PmG[sl * 64 + rloc]);
    }
    // pass 2: weighted combine (Pm/Pl re-read: L2-hot, broadcast in 8-lane grp)
    float acc[8] = {0.f, 0.f, 0.f, 0.f, 0.f, 0.f, 0.f, 0.f};
    float ls = 0.f;
    for (int i = 0; i < nc; ++i) {
        const int sl = b * NSPB + i * (68 - 4 * i) + qb - 8 * i;
        const float wsc = exp2f(PmG[sl * 64 + rloc] - mm);
        const half8 po = *(const half8*)&PoG[((size_t)sl * 64 + rloc) * 64 + d0];
        #pragma unroll
        for (int j = 0; j < 8; ++j) acc[j] += wsc * (float)po[j];
        ls += wsc * PlG[sl * 64 + rloc];
    }
    const float il = 1.f / ls;
    const size_t obase = ((size_t)b * SEQ + qb * QBLK + rloc) * HD + d0;
    if (isbf) {
        __hip_bfloat16* Ob = (__hip_bfloat16*)outp;
        #pragma unroll
        for (int j = 0; j < 8; ++j) Ob[obase + j] = __float2bfloat16(acc[j] * il);
    } else {
        float* Of = (float*)outp;
        #pragma unroll
        for (int j = 0; j < 8; ++j) Of[obase + j] = acc[j] * il;
    }
}

extern "C" void kernel_launch(void* const* d_in, const int* in_sizes, int n_in,
                              void* d_out, int out_size, void* d_ws, size_t ws_size,
                              hipStream_t stream)
{
    const void* x  = d_in[0];
    const void* Wq = d_in[1];
    const void* Wk = d_in[2];
    const void* Wv = d_in[3];

    const size_t N = (size_t)BATCH * SEQ * HD;          // 1,048,576
    int*      flag = (int*)d_ws;
    _Float16* Qh   = (_Float16*)((char*)d_ws + 256);    // 3 x 2 MB fp16
    _Float16* Kh   = Qh + N;
    _Float16* Vth  = Kh + N;
    _Float16* Wt   = Vth + N;                           // 384 KB fp16 frag-ordered
    float*    PmG  = (float*)(Wt + 192 * 1024);         // 288 KB
    float*    PlG  = PmG + (size_t)NSLOT * 64;          // 288 KB
    _Float16* PoG  = (_Float16*)(PlG + (size_t)NSLOT * 64);  // 9.4 MB fp16

    // w_to_fp16t self-detects dtype (fused) and publishes the flag.
    w_to_fp16t<<<96, 256, 0, stream>>>((const unsigned short*)x,
                                       Wq, Wk, Wv, flag, Wt);

    qkv_gemm<<<BATCH * SEQ / BM, 256, 0, stream>>>(x, Wt, flag, Qh, Kh, Vth);

    attn_split<<<dim3(NSPB, BATCH), 256, 0, stream>>>(Qh, Kh, Vth,
                                                      PoG, PmG, PlG);

    attn_merge<<<dim3(SEQ / QBLK, BATCH, 4), 128, 0, stream>>>(PoG, PmG, PlG,
                                                               flag, d_out);
}